// Round 7
// baseline (391.929 us; speedup 1.0000x reference)
//
#include <hip/hip_runtime.h>
#include <hip/hip_bf16.h>

// N=50000 nodes, E=800000 edges, D=128, F_IN=8, C=2
// Output float32: [probs E*2 | bbox_pairs E*8 | bbox_index_pairs E*2]

typedef __attribute__((ext_vector_type(8))) short short8;
typedef __attribute__((ext_vector_type(4))) float f32x4;

__device__ inline ushort f2bf(float f) {
    union { __hip_bfloat16 h; ushort u; } cv;
    cv.h = __float2bfloat16(f);
    return cv.u;
}
__device__ inline float bf2f(ushort u) {
    union { float f; uint u; } c;
    c.u = ((uint)u) << 16;
    return c.f;
}

// ---------------- CSR build ----------------
__global__ void k_zero(int* __restrict__ p, int n) {
    int i = blockIdx.x * blockDim.x + threadIdx.x;
    if (i < n) p[i] = 0;
}

__global__ void k_hist(const int* __restrict__ col, int* __restrict__ cnt, int E) {
    int e = blockIdx.x * blockDim.x + threadIdx.x;
    if (e < E) atomicAdd(&cnt[col[e]], 1);
}

__global__ __launch_bounds__(1024) void k_scan(const int* __restrict__ cnt,
                                               int* __restrict__ ptr, int N) {
    __shared__ int sums[1024];
    int tid = threadIdx.x;
    int chunk = (N + 1023) / 1024;
    int lo = tid * chunk;
    int hi = min(lo + chunk, N);
    int s = 0;
    for (int i = lo; i < hi; ++i) s += cnt[i];
    sums[tid] = s;
    __syncthreads();
    for (int off = 1; off < 1024; off <<= 1) {
        int v = (tid >= off) ? sums[tid - off] : 0;
        __syncthreads();
        sums[tid] += v;
        __syncthreads();
    }
    int run = (tid > 0) ? sums[tid - 1] : 0;
    for (int i = lo; i < hi; ++i) { ptr[i] = run; run += cnt[i]; }
    if (tid == 1023) ptr[N] = run;
}

__global__ void k_dinv(const int* __restrict__ cnt, float* __restrict__ dinv, int n) {
    int i = blockIdx.x * blockDim.x + threadIdx.x;
    if (i < n) dinv[i] = rsqrtf(1.0f + (float)cnt[i]);
}

__global__ void k_fill(const int* __restrict__ row, const int* __restrict__ col,
                       const float* __restrict__ dinv, const int* __restrict__ ptr,
                       int* __restrict__ cursor, int* __restrict__ esrc,
                       float* __restrict__ enorm, int E) {
    int e = blockIdx.x * blockDim.x + threadIdx.x;
    if (e >= E) return;
    int r = row[e], c = col[e];
    int p = ptr[c] + atomicAdd(&cursor[c], 1);
    esrc[p] = r;
    enorm[p] = dinv[r] * dinv[c];
}

// ---------------- weight prep ----------------
__global__ void k_prepW(const float* __restrict__ W, ushort* __restrict__ Wt) {
    int tid = blockIdx.x * blockDim.x + threadIdx.x;
    if (tid >= 128 * 256) return;
    int n = tid >> 8, k = tid & 255;
    Wt[tid] = f2bf(W[k * 128 + n]);
}
__global__ void k_prepW2(const float* __restrict__ W, ushort* __restrict__ Wt) {
    int tid = blockIdx.x * blockDim.x + threadIdx.x;
    if (tid >= 128 * 128) return;
    int n = tid >> 7, k = tid & 127;
    Wt[tid] = f2bf(W[k * 128 + n]);
}

// ---------------- layer-1 aggregate on raw features [N,8] ----------------
__global__ __launch_bounds__(256) void k_agg8(const float* __restrict__ feat,
                                              const float* __restrict__ dinv,
                                              const int* __restrict__ ptr,
                                              const int* __restrict__ esrc,
                                              const float* __restrict__ enorm,
                                              float* __restrict__ aggF, int N) {
    int lane8 = threadIdx.x & 7;
    int node = blockIdx.x * 32 + (threadIdx.x >> 3);
    if (node >= N) return;
    float d = dinv[node];
    float acc = feat[(size_t)node * 8 + lane8] * d * d;
    int i = ptr[node], end = ptr[node + 1];
    for (; i < end; ++i) {
        acc += feat[(size_t)esrc[i] * 8 + lane8] * enorm[i];
    }
    aggF[(size_t)node * 8 + lane8] = acc;
}

// ---------------- layer-1 GEMM: x1 = bf16(relu(aggF[N,8] @ W1 + b1)) ----------------
__global__ __launch_bounds__(256) void k_gemm1(const float* __restrict__ aggF,
                                               const float* __restrict__ W1,
                                               const float* __restrict__ b1,
                                               ushort* __restrict__ x1, int total) {
    int tid = blockIdx.x * blockDim.x + threadIdx.x;
    if (tid >= total) return;
    int n = tid >> 7, j = tid & 127;
    float acc = b1[j];
#pragma unroll
    for (int k = 0; k < 8; ++k) acc += aggF[(size_t)n * 8 + k] * W1[k * 128 + j];
    x1[tid] = f2bf(fmaxf(acc, 0.f));
}

// ---------------- layer-2 GEMM via MFMA: h2 = x1[N,128] @ W2 (bf16 out) ----------------
// Block: 256 thr = 4 waves, 128 nodes. Wave: 32 nodes (2 A-sets) x 128 cols, K=128.
__global__ __launch_bounds__(256) void k_gemm2(const ushort* __restrict__ x1,
                                               const ushort* __restrict__ W2t,
                                               ushort* __restrict__ h2, int N) {
    __shared__ ushort ldsW[128 * 128];   // 32 KB, XOR-swizzled (256B rows)
    const int tid = threadIdx.x;
    const int wave = tid >> 6, lane = tid & 63;
    const int m = lane & 15, kb = lane >> 4;
    const int nbase = blockIdx.x * 128 + wave * 32;

    const int na0 = min(nbase + m, N - 1);
    const int na1 = min(nbase + 16 + m, N - 1);
    short8 a0[4], a1[4];
#pragma unroll
    for (int kk = 0; kk < 4; ++kk) {
        const int ko = kk * 32 + kb * 8;
        a0[kk] = *reinterpret_cast<const short8*>(&x1[(size_t)na0 * 128 + ko]);
        a1[kk] = *reinterpret_cast<const short8*>(&x1[(size_t)na1 * 128 + ko]);
    }

    {
        char* lb = reinterpret_cast<char*>(ldsW);
        const short8* wg = reinterpret_cast<const short8*>(W2t);
#pragma unroll
        for (int i = 0; i < 8; ++i) {
            const int g = i * 256 + tid;
            const int bo = g * 16;
            const int swz = bo ^ (((bo >> 8) & 7) << 4);
            *reinterpret_cast<short8*>(lb + swz) = wg[g];
        }
    }
    __syncthreads();

    f32x4 acc0[8], acc1[8];
#pragma unroll
    for (int t = 0; t < 8; ++t) {
        acc0[t] = (f32x4){0.f, 0.f, 0.f, 0.f};
        acc1[t] = (f32x4){0.f, 0.f, 0.f, 0.f};
    }

    const char* lbr = reinterpret_cast<const char*>(ldsW);
    const int mswz = (m & 7) << 4;
#pragma unroll
    for (int kk = 0; kk < 4; ++kk) {
#pragma unroll
        for (int t = 0; t < 8; ++t) {
            const int bo = (t * 16 + m) * 256 + kk * 64 + kb * 16;
            const short8 b = *reinterpret_cast<const short8*>(lbr + (bo ^ mswz));
            acc0[t] = __builtin_amdgcn_mfma_f32_16x16x32_bf16(a0[kk], b, acc0[t], 0, 0, 0);
            acc1[t] = __builtin_amdgcn_mfma_f32_16x16x32_bf16(a1[kk], b, acc1[t], 0, 0, 0);
        }
    }

    // C layout: col = t*16 + m, row(node within set) = kb*4 + r
#pragma unroll
    for (int r = 0; r < 4; ++r) {
        const int n_0 = nbase + kb * 4 + r;
        if (n_0 < N) {
#pragma unroll
            for (int t = 0; t < 8; ++t) h2[(size_t)n_0 * 128 + t * 16 + m] = f2bf(acc0[t][r]);
        }
        const int n_1 = nbase + 16 + kb * 4 + r;
        if (n_1 < N) {
#pragma unroll
            for (int t = 0; t < 8; ++t) h2[(size_t)n_1 * 128 + t * 16 + m] = f2bf(acc1[t][r]);
        }
    }
}

// ---------------- layer-2 aggregate (bf16 rows): xbf = bf16(relu(A~ h2 + b2)) ----------------
__global__ __launch_bounds__(256) void k_gather2(const ushort* __restrict__ h2,
                                                 const float* __restrict__ dinv,
                                                 const int* __restrict__ ptr,
                                                 const int* __restrict__ esrc,
                                                 const float* __restrict__ enorm,
                                                 const float* __restrict__ b2,
                                                 ushort* __restrict__ xbf, int N) {
    int lane16 = threadIdx.x & 15;
    int node = blockIdx.x * 16 + (threadIdx.x >> 4);
    if (node >= N) return;
    float d = dinv[node];
    float dd = d * d;
    float acc[8];
    {
        const short8 v = *reinterpret_cast<const short8*>(&h2[(size_t)node * 128 + lane16 * 8]);
#pragma unroll
        for (int i = 0; i < 8; ++i) acc[i] = bf2f((ushort)v[i]) * dd;
    }
    int i = ptr[node], end = ptr[node + 1];
    for (; i < end; ++i) {
        const int s = esrc[i];
        const float nm = enorm[i];
        const short8 v = *reinterpret_cast<const short8*>(&h2[(size_t)s * 128 + lane16 * 8]);
#pragma unroll
        for (int q = 0; q < 8; ++q) acc[q] += bf2f((ushort)v[q]) * nm;
    }
    short8 r;
#pragma unroll
    for (int q = 0; q < 8; ++q) {
        r[q] = (short)f2bf(fmaxf(acc[q] + b2[lane16 * 8 + q], 0.f));
    }
    *reinterpret_cast<short8*>(&xbf[(size_t)node * 128 + lane16 * 8]) = r;
}

// ---------------- edge MLP via MFMA, LDS-staged weights, 2 A-sets/wave ----------------
// Block: 512 threads = 8 waves, 256 edges. Wave: 32 edges x 128 hidden, K=256.
#define EB2 256

#define EPILOG(ACC, EOFF)                                                            \
    {                                                                                \
        float p0[4] = {0.f, 0.f, 0.f, 0.f};                                          \
        float p1[4] = {0.f, 0.f, 0.f, 0.f};                                          \
        _Pragma("unroll") for (int t = 0; t < 8; ++t) {                              \
            const int n = t * 16 + m;                                                \
            const float bn = lin1b[n];                                               \
            const float2 wf = *reinterpret_cast<const float2*>(&linfW[n * 2]);       \
            _Pragma("unroll") for (int r = 0; r < 4; ++r) {                          \
                const float hv = fmaxf(ACC[t][r] + bn, 0.f);                         \
                p0[r] += hv * wf.x;                                                  \
                p1[r] += hv * wf.y;                                                  \
            }                                                                        \
        }                                                                            \
        _Pragma("unroll") for (int s = 1; s < 16; s <<= 1) {                         \
            _Pragma("unroll") for (int r = 0; r < 4; ++r) {                          \
                p0[r] += __shfl_xor(p0[r], s);                                       \
                p1[r] += __shfl_xor(p1[r], s);                                       \
            }                                                                        \
        }                                                                            \
        if (m < 4) {                                                                 \
            const int er = ebase + (EOFF) + (kb << 2) + m;                           \
            if (er < E) {                                                            \
                const float z0 = p0[m] + linfb[0];                                   \
                const float z1 = p1[m] + linfb[1];                                   \
                const float mx = fmaxf(z0, z1);                                      \
                const float lse = mx + logf(expf(z0 - mx) + expf(z1 - mx));          \
                *reinterpret_cast<float2*>(&out_probs[(size_t)er * 2]) =             \
                    make_float2(z0 - lse, z1 - lse);                                 \
            }                                                                        \
        }                                                                            \
    }

__global__ __launch_bounds__(512) void k_edge_mfma(const ushort* __restrict__ xbf,
                                                   const ushort* __restrict__ Wt,
                                                   const float* __restrict__ lin1b,
                                                   const float* __restrict__ linfW,
                                                   const float* __restrict__ linfb,
                                                   const float* __restrict__ bboxes,
                                                   const int* __restrict__ bidx,
                                                   const int* __restrict__ row,
                                                   const int* __restrict__ col,
                                                   float* __restrict__ out_probs,
                                                   float* __restrict__ out_bbox,
                                                   float* __restrict__ out_bidx,
                                                   int E) {
    __shared__ ushort ldsW[128 * 256];   // 64 KB, XOR-swizzled (512B rows)
    const int tid = threadIdx.x;
    const int wave = tid >> 6, lane = tid & 63;
    const int e0 = blockIdx.x * EB2;
    const int m = lane & 15;
    const int kb = lane >> 4;
    const int ebase = e0 + wave * 32;

    const int ec0 = min(ebase + m, E - 1);
    const int ec1 = min(ebase + 16 + m, E - 1);
    const int src0 = row[ec0], dst0 = col[ec0];
    const int src1 = row[ec1], dst1 = col[ec1];

    short8 a0[8], a1[8];
#pragma unroll
    for (int kk = 0; kk < 8; ++kk) {
        const int kloc = kk * 32 + kb * 8;
        const int koff = kloc & 127;
        const int n0 = (kloc < 128) ? src0 : dst0;
        const int n1 = (kloc < 128) ? src1 : dst1;
        a0[kk] = *reinterpret_cast<const short8*>(&xbf[(size_t)n0 * 128 + koff]);
        a1[kk] = *reinterpret_cast<const short8*>(&xbf[(size_t)n1 * 128 + koff]);
    }

    {
        char* lb = reinterpret_cast<char*>(ldsW);
        const short8* wg = reinterpret_cast<const short8*>(Wt);
#pragma unroll
        for (int i = 0; i < 8; ++i) {
            const int g = i * 512 + tid;
            const int bo = g * 16;
            const int swz = bo ^ (((bo >> 9) & 7) << 4);
            *reinterpret_cast<short8*>(lb + swz) = wg[g];
        }
    }
    __syncthreads();

    f32x4 acc0[8], acc1[8];
#pragma unroll
    for (int t = 0; t < 8; ++t) {
        acc0[t] = (f32x4){0.f, 0.f, 0.f, 0.f};
        acc1[t] = (f32x4){0.f, 0.f, 0.f, 0.f};
    }

    const char* lbr = reinterpret_cast<const char*>(ldsW);
    const int mswz = (m & 7) << 4;
#pragma unroll
    for (int kk = 0; kk < 8; ++kk) {
        const int kloc = kk * 32 + kb * 8;
#pragma unroll
        for (int t = 0; t < 8; ++t) {
            const int bo = ((t * 16 + m) * 256 + kloc) * 2;
            const short8 b = *reinterpret_cast<const short8*>(lbr + (bo ^ mswz));
            acc0[t] = __builtin_amdgcn_mfma_f32_16x16x32_bf16(a0[kk], b, acc0[t], 0, 0, 0);
            acc1[t] = __builtin_amdgcn_mfma_f32_16x16x32_bf16(a1[kk], b, acc1[t], 0, 0, 0);
        }
    }

    EPILOG(acc0, 0)
    EPILOG(acc1, 16)

    // bbox_pairs [E,8] and bbox_index_pairs [E,2]
    for (int idx = tid; idx < EB2 * 8; idx += 512) {
        const int ee = idx >> 3, q = idx & 7;
        const int e2 = e0 + ee;
        if (e2 < E) {
            const int node = (q < 4) ? row[e2] : col[e2];
            out_bbox[(size_t)e2 * 8 + q] = bboxes[(size_t)node * 4 + (q & 3)];
        }
    }
    for (int idx = tid; idx < EB2 * 2; idx += 512) {
        const int ee = idx >> 1, c = idx & 1;
        const int e2 = e0 + ee;
        if (e2 < E) {
            const int node = c ? col[e2] : row[e2];
            out_bidx[(size_t)e2 * 2 + c] = (float)bidx[node];
        }
    }
}

extern "C" void kernel_launch(void* const* d_in, const int* in_sizes, int n_in,
                              void* d_out, int out_size, void* d_ws, size_t ws_size,
                              hipStream_t stream) {
    const float* feat   = (const float*)d_in[0];
    const float* bboxes = (const float*)d_in[1];
    const int*   bidx   = (const int*)d_in[2];
    const int*   eidx   = (const int*)d_in[3];
    const float* W1     = (const float*)d_in[4];
    const float* b1     = (const float*)d_in[5];
    const float* W2     = (const float*)d_in[6];
    const float* b2     = (const float*)d_in[7];
    const float* lin1W  = (const float*)d_in[8];
    const float* lin1b  = (const float*)d_in[9];
    const float* linfW  = (const float*)d_in[10];
    const float* linfb  = (const float*)d_in[11];

    const int N = in_sizes[0] / 8;
    const int E = in_sizes[3] / 2;
    const int* row = eidx;        // sources
    const int* col = eidx + E;    // targets

    size_t Np = ((size_t)N + 255) & ~255ull;
    size_t Ep = ((size_t)E + 255) & ~255ull;
    size_t A8 = (((size_t)N * 8) + 255) & ~255ull;
    int*    cnt    = (int*)d_ws;                 // Np
    int*    cursor = cnt + Np;                   // Np
    int*    ptr    = cursor + Np;                // Np+256
    float*  dinv   = (float*)(ptr + Np + 256);   // Np
    int*    esrc   = (int*)(dinv + Np);          // Ep
    float*  enorm  = (float*)(esrc + Ep);        // Ep
    float*  aggF   = enorm + Ep;                 // A8 f32
    ushort* x1     = (ushort*)(aggF + A8);       // N*128 bf16
    ushort* h2     = x1 + (size_t)N * 128;       // N*128 bf16
    ushort* xbf    = h2 + (size_t)N * 128;       // N*128 bf16
    ushort* Wt     = xbf + (size_t)N * 128;      // 128*256 bf16
    ushort* W2t    = Wt + 128 * 256;             // 128*128 bf16

    float* out       = (float*)d_out;
    float* out_probs = out;                   // E*2
    float* out_bbox  = out + (size_t)E * 2;   // E*8
    float* out_bidx  = out + (size_t)E * 10;  // E*2

    const int total = N * 128;
    const int B = 256;

    // CSR build + dinv + weight prep
    k_zero<<<(int)((2 * Np + B - 1) / B), B, 0, stream>>>(cnt, (int)(2 * Np));
    k_hist<<<(E + B - 1) / B, B, 0, stream>>>(col, cnt, E);
    k_scan<<<1, 1024, 0, stream>>>(cnt, ptr, N);
    k_dinv<<<(N + B - 1) / B, B, 0, stream>>>(cnt, dinv, N);
    k_fill<<<(E + B - 1) / B, B, 0, stream>>>(row, col, dinv, ptr, cursor, esrc, enorm, E);
    k_prepW<<<(128 * 256 + B - 1) / B, B, 0, stream>>>(lin1W, Wt);
    k_prepW2<<<(128 * 128 + B - 1) / B, B, 0, stream>>>(W2, W2t);

    // layer 1 (aggregate-first on [N,8], then tiny GEMM)
    k_agg8<<<(N + 31) / 32, B, 0, stream>>>(feat, dinv, ptr, esrc, enorm, aggF, N);
    k_gemm1<<<(total + B - 1) / B, B, 0, stream>>>(aggF, W1, b1, x1, total);

    // layer 2 (MFMA GEMM, then bf16 gather)
    k_gemm2<<<(N + 127) / 128, B, 0, stream>>>(x1, W2t, h2, N);
    k_gather2<<<(N + 15) / 16, B, 0, stream>>>(h2, dinv, ptr, esrc, enorm, b2, xbf, N);

    // edge MLP (MFMA, LDS weights) + outputs
    k_edge_mfma<<<(E + EB2 - 1) / EB2, 512, 0, stream>>>(xbf, Wt, lin1b, linfW, linfb,
                                                         bboxes, bidx, row, col,
                                                         out_probs, out_bbox, out_bidx, E);
}